// Round 5
// baseline (45.572 us; speedup 1.0000x reference)
//
#include <hip/hip_runtime.h>
#include <cstdint>
#include <cstddef>

// HyperNetwork via MFMA, registers-only apply:
//   Out[b,c,f] = sum_n X[b,c,n] * W_eff[c,f,n] + b_eff[c,f]
//   Kernel A: W_eff[c] = W_out(9x64) @ W_in[c](64x256) emitted as bf16 hi/lo
//             MFMA A-fragments into d_ws + b_eff.
//   Kernel B: 2048 blocks = (bq, c); 4 independent waves/block, 16 b-rows per
//             wave. X B-fragments loaded DIRECTLY from global (lane's 8
//             contiguous floats), hi/lo split in-reg, 3-term bf16 MFMA.
//             Zero LDS, zero barriers.

#define CC 512
#define NZ 256
#define ZD 64
#define NF 9
#define BB 256

typedef __attribute__((ext_vector_type(4))) float f32x4;
typedef __attribute__((ext_vector_type(8))) short bf16x8;
typedef __attribute__((ext_vector_type(4))) unsigned int u32x4;

__device__ __forceinline__ unsigned short f2bf(float f) {   // RTNE (kernel A)
  unsigned int u = __builtin_bit_cast(unsigned int, f);
  unsigned int r = (u + 0x7fffu + ((u >> 16) & 1u)) >> 16;
  return (unsigned short)r;
}
__device__ __forceinline__ float bf2f(unsigned short u) {
  unsigned int x = ((unsigned int)u) << 16;
  return __builtin_bit_cast(float, x);
}

// ---------------- Kernel A: W_eff -> bf16 hi/lo fragments + bias ----------
__global__ __launch_bounds__(256, 2)
void weff_build(const float* __restrict__ W_in, const float* __restrict__ b_in,
                const float* __restrict__ W_out, const float* __restrict__ b_out,
                unsigned short* __restrict__ ws_wh,
                unsigned short* __restrict__ ws_wl,
                float* __restrict__ ws_b)
{
  __shared__ float w_lds[NF * NZ];
  const int c = blockIdx.x, t = threadIdx.x;
  {
    float acc[NF];
#pragma unroll
    for (int f = 0; f < NF; ++f) acc[f] = 0.f;
    const float* wi = W_in + (size_t)c * ZD * NZ + t;
#pragma unroll 8
    for (int zz = 0; zz < ZD; ++zz) {
      float v = wi[(size_t)zz * NZ];              // 1KB coalesced per iter
#pragma unroll
      for (int f = 0; f < NF; ++f) acc[f] += W_out[f * ZD + zz] * v;  // s_load
    }
#pragma unroll
    for (int f = 0; f < NF; ++f) w_lds[f * NZ + t] = acc[f];
  }
  if (t < 16) {
    float bacc = 0.f;
    if (t < NF) {
      bacc = b_out[t];
      for (int zz = 0; zz < ZD; ++zz)
        bacc += b_in[(size_t)c * ZD + zz] * W_out[t * ZD + zz];
    }
    ws_b[c * 16 + t] = bacc;                      // f>=9 zeroed
  }
  __syncthreads();

  // Emit A-fragments: lane l holds W[f=l&15][n = ks*32 + (l>>4)*8 + j]
#pragma unroll
  for (int p = 0; p < 2; ++p) {
    const int u = p * 256 + t;
    const int ks = u >> 6, l = u & 63;
    const int f = l & 15, g = l >> 4;
    bf16x8 hv, lv;
#pragma unroll
    for (int j = 0; j < 8; ++j) {
      float v = (f < NF) ? w_lds[f * NZ + ks * 32 + g * 8 + j] : 0.f;
      unsigned short hh = f2bf(v);
      hv[j] = (short)hh;
      lv[j] = (short)f2bf(v - bf2f(hh));
    }
    const size_t off = ((size_t)(c * 8 + ks) * 64 + l) * 8;
    *(bf16x8*)(ws_wh + off) = hv;                 // coalesced 16B/lane
    *(bf16x8*)(ws_wl + off) = lv;
  }
}

// ---------------- Kernel B: registers-only MFMA apply ----------------
__device__ __forceinline__ void split8(f32x4 x0, f32x4 x1,
                                       bf16x8* xh, bf16x8* xl) {
  unsigned u[8];
  unsigned r[8];
#pragma unroll
  for (int j = 0; j < 4; ++j) {
    u[j]     = __builtin_bit_cast(unsigned, x0[j]);
    u[4 + j] = __builtin_bit_cast(unsigned, x1[j]);
  }
#pragma unroll
  for (int j = 0; j < 8; ++j) {
    float hf = __builtin_bit_cast(float, u[j] & 0xffff0000u);   // trunc hi
    float xf = (j < 4) ? x0[j] : x1[j - 4];
    r[j] = __builtin_bit_cast(unsigned, xf - hf);               // exact resid
  }
  u32x4 h, l;
#pragma unroll
  for (int d = 0; d < 4; ++d) {
    h[d] = __builtin_amdgcn_perm(u[2 * d + 1], u[2 * d], 0x07060302u);
    l[d] = __builtin_amdgcn_perm(r[2 * d + 1], r[2 * d], 0x07060302u);
  }
  *xh = __builtin_bit_cast(bf16x8, h);
  *xl = __builtin_bit_cast(bf16x8, l);
}

__global__ __launch_bounds__(256, 4)
void hyper_mfma2(const float* __restrict__ z,
                 const unsigned short* __restrict__ ws_wh,
                 const unsigned short* __restrict__ ws_wl,
                 const float* __restrict__ ws_b,
                 float* __restrict__ out)
{
  const int blk = blockIdx.x;
  const int c  = blk & (CC - 1);    // same-c blocks 512 apart -> same XCD L2
  const int bq = blk >> 9;          // 0..3
  const int t = threadIdx.x;
  const int lane = t & 63;
  const int w = t >> 6;
  const int g = lane >> 4;
  const int l4 = lane & 15;

  // Preload W fragments (8 k-steps, hi+lo) -> 64 VGPRs (1KB coalesced/instr)
  bf16x8 wh[8], wl[8];
#pragma unroll
  for (int ks = 0; ks < 8; ++ks) {
    const size_t off = ((size_t)(c * 8 + ks) * 64 + lane) * 8;
    wh[ks] = *(const bf16x8*)(ws_wh + off);
    wl[ks] = *(const bf16x8*)(ws_wl + off);
  }
  const f32x4 bv = *(const f32x4*)(ws_b + c * 16 + g * 4);

  // This wave's 16 b-rows; lane's 8-float slice of row (l4)
  const int b = bq * 64 + w * 16 + l4;
  const float* xr = z + ((size_t)b * CC + c) * NZ + g * 8;

  f32x4 acc = {0.f, 0.f, 0.f, 0.f};
#pragma unroll
  for (int ks = 0; ks < 8; ++ks) {
    f32x4 x0 = *(const f32x4*)(xr + ks * 32);       // offset: ks*128 imm
    f32x4 x1 = *(const f32x4*)(xr + ks * 32 + 4);
    bf16x8 xh, xl;
    split8(x0, x1, &xh, &xl);
    acc = __builtin_amdgcn_mfma_f32_16x16x32_bf16(wh[ks], xh, acc, 0, 0, 0);
    acc = __builtin_amdgcn_mfma_f32_16x16x32_bf16(wl[ks], xh, acc, 0, 0, 0);
    acc = __builtin_amdgcn_mfma_f32_16x16x32_bf16(wh[ks], xl, acc, 0, 0, 0);
  }

  // D[row=f][col=b]: lane holds f = g*4 + reg (g<2), f=8 at g==2,reg==0
  float* ob = out + ((size_t)b * CC + c) * NF;
  if (g < 2) {
#pragma unroll
    for (int reg = 0; reg < 4; ++reg)
      ob[g * 4 + reg] = acc[reg] + bv[reg];
  } else if (g == 2) {
    ob[8] = acc[0] + bv[0];
  }
}

// ---------------- Fallback (R1 kernel) if ws too small ----------------
#define XROW 260
__device__ __forceinline__ void gload_lds16(const float* g, float* l) {
  __builtin_amdgcn_global_load_lds(
      (const __attribute__((address_space(1))) void*)g,
      (__attribute__((address_space(3))) void*)l, 16, 0, 0);
}

__global__ __launch_bounds__(256, 2)
void hyper_fused(const float* __restrict__ z, const float* __restrict__ W_in,
                 const float* __restrict__ b_in, const float* __restrict__ W_out,
                 const float* __restrict__ b_out, float* __restrict__ out)
{
  __shared__ __align__(16) float w_lds[NF * NZ];
  __shared__ float b_lds[16];
  __shared__ __align__(16) float x_lds[64 * XROW];
  float* part = x_lds;
  const int c = blockIdx.x, t = threadIdx.x, lane = t & 63, w = t >> 6;
  {
    float acc[NF];
#pragma unroll
    for (int f = 0; f < NF; ++f) acc[f] = 0.f;
    const float* wi = W_in + (size_t)c * ZD * NZ + t;
    for (int zz = 0; zz < ZD; ++zz) {
      float v = wi[(size_t)zz * NZ];
#pragma unroll
      for (int f = 0; f < NF; ++f) acc[f] += W_out[f * ZD + zz] * v;
    }
#pragma unroll
    for (int f = 0; f < NF; ++f) w_lds[f * NZ + t] = acc[f];
  }
  if (t < NF) {
    float bacc = b_out[t];
    for (int zz = 0; zz < ZD; ++zz)
      bacc += b_in[(size_t)c * ZD + zz] * W_out[t * ZD + zz];
    b_lds[t] = bacc;
  }
  __syncthreads();
  for (int bc = 0; bc < 4; ++bc) {
    const int r0 = w * 16;
#pragma unroll
    for (int j = 0; j < 16; ++j) {
      const int r = r0 + j, b = bc * 64 + r;
      gload_lds16(z + ((size_t)b * CC + c) * NZ + lane * 4, &x_lds[r * XROW]);
    }
    __syncthreads();
    float acc[NF];
#pragma unroll
    for (int f = 0; f < NF; ++f) acc[f] = 0.f;
    const int n0 = w * 64;
#pragma unroll
    for (int g4 = 0; g4 < 16; ++g4) {
      f32x4 xvv = *(const f32x4*)&x_lds[lane * XROW + n0 + g4 * 4];
#pragma unroll
      for (int f = 0; f < NF; ++f) {
        f32x4 wf = *(const f32x4*)&w_lds[f * NZ + n0 + g4 * 4];
        acc[f] += xvv.x * wf.x; acc[f] += xvv.y * wf.y;
        acc[f] += xvv.z * wf.z; acc[f] += xvv.w * wf.w;
      }
    }
    __syncthreads();
#pragma unroll
    for (int f = 0; f < NF; ++f) part[(w * 64 + lane) * NF + f] = acc[f];
    __syncthreads();
    const int b = bc * 64 + lane;
    for (int f = w; f < NF; f += 4) {
      float s = part[(0 * 64 + lane) * NF + f] + part[(1 * 64 + lane) * NF + f]
              + part[(2 * 64 + lane) * NF + f] + part[(3 * 64 + lane) * NF + f];
      out[((size_t)b * CC + c) * NF + f] = s + b_lds[f];
    }
    __syncthreads();
  }
}

extern "C" void kernel_launch(void* const* d_in, const int* in_sizes, int n_in,
                              void* d_out, int out_size, void* d_ws, size_t ws_size,
                              hipStream_t stream) {
  const float* z     = (const float*)d_in[0];
  const float* W_in  = (const float*)d_in[1];
  const float* b_in  = (const float*)d_in[2];
  const float* W_out = (const float*)d_in[3];
  const float* b_out = (const float*)d_in[4];
  float* out = (float*)d_out;

  const size_t frag_elems = (size_t)CC * 8 * 64 * 8;           // ushorts (4 MB)
  const size_t ws_need = frag_elems * 2 * sizeof(unsigned short)
                       + (size_t)CC * 16 * sizeof(float);
  if (ws_size >= ws_need) {
    unsigned short* ws_wh = (unsigned short*)d_ws;
    unsigned short* ws_wl = ws_wh + frag_elems;
    float* ws_b = (float*)(ws_wl + frag_elems);
    hipLaunchKernelGGL(weff_build, dim3(CC), dim3(256), 0, stream,
                       W_in, b_in, W_out, b_out, ws_wh, ws_wl, ws_b);
    hipLaunchKernelGGL(hyper_mfma2, dim3(4 * CC), dim3(256), 0, stream,
                       z, ws_wh, ws_wl, ws_b, out);
  } else {
    hipLaunchKernelGGL(hyper_fused, dim3(CC), dim3(256), 0, stream,
                       z, W_in, b_in, W_out, b_out, out);
  }
}

// Round 7
// 35.669 us; speedup vs baseline: 1.2777x; 1.2777x over previous
//
#include <hip/hip_runtime.h>
#include <cstdint>
#include <cstddef>

// HyperNetwork, single fused kernel (verified-paths-only rebuild):
//   Out[b,c,f] = sum_n X[b,c,n] * W_eff[c,f,n] + b_eff[c,f]
//   W_eff[c] = W_out(9x64) @ W_in[c](64x256); b_eff = W_out@b_in[c] + b_out.
//
// One block per channel c (512 blocks, 256 thr):
//   Phase 1a: W_eff[c] -> w_lds (EXACT R4-kernel-A compute; verified).
//   Phase 1b: RTNE hi/lo bf16 fragment emit (EXACT R4 emit loop; verified),
//             destination = LDS fragment buffer instead of global ws.
//   Phase 1c: per-lane fragment load (EXACT R5-kernel-B load; verified),
//             source = LDS fragment buffer.
//   Phase 2:  registers-only MFMA apply over 4 b-quadrants (EXACT R5 loop).

#define CC 512
#define NZ 256
#define ZD 64
#define NF 9

typedef __attribute__((ext_vector_type(4))) float f32x4;
typedef __attribute__((ext_vector_type(8))) short bf16x8;
typedef __attribute__((ext_vector_type(4))) unsigned int u32x4;

__device__ __forceinline__ unsigned short f2bf(float f) {   // RTNE
  unsigned int u = __builtin_bit_cast(unsigned int, f);
  unsigned int r = (u + 0x7fffu + ((u >> 16) & 1u)) >> 16;
  return (unsigned short)r;
}
__device__ __forceinline__ float bf2f(unsigned short u) {
  unsigned int x = ((unsigned int)u) << 16;
  return __builtin_bit_cast(float, x);
}

// split 8 f32 -> bf16 hi (trunc) + bf16 lo (residual) — EXACT R5 split8
__device__ __forceinline__ void split8(f32x4 x0, f32x4 x1,
                                       bf16x8* xh, bf16x8* xl) {
  unsigned u[8], r[8];
#pragma unroll
  for (int j = 0; j < 4; ++j) {
    u[j]     = __builtin_bit_cast(unsigned, x0[j]);
    u[4 + j] = __builtin_bit_cast(unsigned, x1[j]);
  }
#pragma unroll
  for (int j = 0; j < 8; ++j) {
    float hf = __builtin_bit_cast(float, u[j] & 0xffff0000u);
    float xf = (j < 4) ? x0[j] : x1[j - 4];
    r[j] = __builtin_bit_cast(unsigned, xf - hf);
  }
  u32x4 h, l;
#pragma unroll
  for (int d = 0; d < 4; ++d) {
    h[d] = __builtin_amdgcn_perm(u[2 * d + 1], u[2 * d], 0x07060302u);
    l[d] = __builtin_amdgcn_perm(r[2 * d + 1], r[2 * d], 0x07060302u);
  }
  *xh = __builtin_bit_cast(bf16x8, h);
  *xl = __builtin_bit_cast(bf16x8, l);
}

__global__ __launch_bounds__(256, 2)
void hyper_one(const float* __restrict__ z,
               const float* __restrict__ W_in,
               const float* __restrict__ b_in,
               const float* __restrict__ W_out,
               const float* __restrict__ b_out,
               float* __restrict__ out)
{
  __shared__ float w_lds[NF * NZ];                       // 9216 B
  __shared__ float b_lds[16];
  __shared__ __align__(16) unsigned short fh[8 * 64 * 8]; // 8 KB [ks][l][j]
  __shared__ __align__(16) unsigned short fl[8 * 64 * 8]; // 8 KB

  const int c = blockIdx.x;
  const int t = threadIdx.x;
  const int lane = t & 63;
  const int w = t >> 6;
  const int g = lane >> 4;
  const int l4 = lane & 15;

  // ---------- Phase 1a: W_eff[f][n=t] (EXACT R4 kernel-A) ----------
  {
    float acc[NF];
#pragma unroll
    for (int f = 0; f < NF; ++f) acc[f] = 0.f;
    const float* wi = W_in + (size_t)c * ZD * NZ + t;
#pragma unroll 8
    for (int zz = 0; zz < ZD; ++zz) {
      float v = wi[(size_t)zz * NZ];              // 1KB coalesced per iter
#pragma unroll
      for (int f = 0; f < NF; ++f) acc[f] += W_out[f * ZD + zz] * v;  // s_load
    }
#pragma unroll
    for (int f = 0; f < NF; ++f) w_lds[f * NZ + t] = acc[f];
  }
  if (t < 16) {
    float bacc = 0.f;
    if (t < NF) {
      bacc = b_out[t];
      for (int zz = 0; zz < ZD; ++zz)
        bacc += b_in[(size_t)c * ZD + zz] * W_out[t * ZD + zz];
    }
    b_lds[t] = bacc;
  }
  __syncthreads();

  // ---------- Phase 1b: fragment emit (EXACT R4 emit, dest = LDS) ----------
#pragma unroll
  for (int p = 0; p < 2; ++p) {
    const int u = p * 256 + t;
    const int ks = u >> 6, l = u & 63;
    const int f = l & 15, g2 = l >> 4;
    bf16x8 hv, lv;
#pragma unroll
    for (int j = 0; j < 8; ++j) {
      float v = (f < NF) ? w_lds[f * NZ + ks * 32 + g2 * 8 + j] : 0.f;
      unsigned short hh = f2bf(v);
      hv[j] = (short)hh;
      lv[j] = (short)f2bf(v - bf2f(hh));
    }
    *(bf16x8*)&fh[(ks * 64 + l) * 8] = hv;
    *(bf16x8*)&fl[(ks * 64 + l) * 8] = lv;
  }
  __syncthreads();

  // ---------- Phase 1c: per-lane fragment load (EXACT R5 load, src = LDS) ----
  bf16x8 wh[8], wl[8];
#pragma unroll
  for (int ks = 0; ks < 8; ++ks) {
    wh[ks] = *(const bf16x8*)&fh[(ks * 64 + lane) * 8];
    wl[ks] = *(const bf16x8*)&fl[(ks * 64 + lane) * 8];
  }
  const f32x4 bv = {b_lds[g * 4 + 0], b_lds[g * 4 + 1],
                    b_lds[g * 4 + 2], b_lds[g * 4 + 3]};

  // ---------- Phase 2: registers-only MFMA apply (EXACT R5) ----------
#pragma unroll
  for (int bq = 0; bq < 4; ++bq) {
    const int b = bq * 64 + w * 16 + l4;
    const float* xr = z + ((size_t)b * CC + c) * NZ + g * 8;

    f32x4 acc = {0.f, 0.f, 0.f, 0.f};
#pragma unroll
    for (int ks = 0; ks < 8; ++ks) {
      f32x4 x0 = *(const f32x4*)(xr + ks * 32);
      f32x4 x1 = *(const f32x4*)(xr + ks * 32 + 4);
      bf16x8 xh, xl;
      split8(x0, x1, &xh, &xl);
      acc = __builtin_amdgcn_mfma_f32_16x16x32_bf16(wh[ks], xh, acc, 0, 0, 0);
      acc = __builtin_amdgcn_mfma_f32_16x16x32_bf16(wl[ks], xh, acc, 0, 0, 0);
      acc = __builtin_amdgcn_mfma_f32_16x16x32_bf16(wh[ks], xl, acc, 0, 0, 0);
    }

    // D[row=f=g*4+reg][col=b=l4] (verified C/D map)
    float* ob = out + ((size_t)b * CC + c) * NF;
    if (g < 2) {
#pragma unroll
      for (int reg = 0; reg < 4; ++reg)
        ob[g * 4 + reg] = acc[reg] + bv[reg];
    } else if (g == 2) {
      ob[8] = acc[0] + bv[0];
    }
  }
}

extern "C" void kernel_launch(void* const* d_in, const int* in_sizes, int n_in,
                              void* d_out, int out_size, void* d_ws, size_t ws_size,
                              hipStream_t stream) {
  const float* z     = (const float*)d_in[0];
  const float* W_in  = (const float*)d_in[1];
  const float* b_in  = (const float*)d_in[2];
  const float* W_out = (const float*)d_in[3];
  const float* b_out = (const float*)d_in[4];
  float* out = (float*)d_out;

  hipLaunchKernelGGL(hyper_one, dim3(CC), dim3(256), 0, stream,
                     z, W_in, b_in, W_out, b_out, out);
}